// Round 2
// baseline (2380.587 us; speedup 1.0000x reference)
//
#include <hip/hip_runtime.h>
#include <math.h>

#define NB 4
#define NS 1024
#define ND 1024
#define NH 16
#define NDH 64

__device__ __forceinline__ unsigned short f2b(float f) {
    unsigned u = __float_as_uint(f);
    unsigned r = (u + 0x7fffu + ((u >> 16) & 1u)) >> 16;   // RNE
    return (unsigned short)r;
}
__device__ __forceinline__ float b2f(unsigned short h) {
    return __uint_as_float(((unsigned)h) << 16);
}

// ---------------------------------------------------------------------------
// Kernel 1: q projection with variance propagation.
//   q     = x @ Wm^T
//   var_q = var_x @ (Wv + Wm^2)^T + x^2 @ Wv^T
// Output written in [B,H,S,DH] layout into workspace.
// ---------------------------------------------------------------------------
__global__ __launch_bounds__(256)
void qproj_kernel(const float* __restrict__ x, const float* __restrict__ vx,
                  const float* __restrict__ Wm, const float* __restrict__ Wv,
                  float* __restrict__ q_ws, float* __restrict__ vq_ws)
{
    __shared__ float sX[16][64];
    __shared__ float sVX[16][64];
    __shared__ float sWM[16][64];
    __shared__ float sWV[16][64];

    const int tid = threadIdx.x;
    const int tn = tid & 15;
    const int tm = tid >> 4;
    const int n0 = blockIdx.x * 64;
    const int m0 = blockIdx.y * 64;
    const int lr = tid >> 2;
    const int lk = (tid & 3) << 2;

    float accq[4][4] = {};
    float accv[4][4] = {};

    const float* xrow  = x  + (size_t)(m0 + lr) * ND + lk;
    const float* vrow  = vx + (size_t)(m0 + lr) * ND + lk;
    const float* wmrow = Wm + (size_t)(n0 + lr) * ND + lk;
    const float* wvrow = Wv + (size_t)(n0 + lr) * ND + lk;

    for (int kt = 0; kt < ND / 16; ++kt) {
        const float4 xa  = *(const float4*)(xrow  + kt * 16);
        const float4 va  = *(const float4*)(vrow  + kt * 16);
        const float4 wm4 = *(const float4*)(wmrow + kt * 16);
        const float4 wv4 = *(const float4*)(wvrow + kt * 16);
        __syncthreads();
        sX [lk+0][lr] = xa.x;  sX [lk+1][lr] = xa.y;  sX [lk+2][lr] = xa.z;  sX [lk+3][lr] = xa.w;
        sVX[lk+0][lr] = va.x;  sVX[lk+1][lr] = va.y;  sVX[lk+2][lr] = va.z;  sVX[lk+3][lr] = va.w;
        sWM[lk+0][lr] = wm4.x; sWM[lk+1][lr] = wm4.y; sWM[lk+2][lr] = wm4.z; sWM[lk+3][lr] = wm4.w;
        sWV[lk+0][lr] = wv4.x; sWV[lk+1][lr] = wv4.y; sWV[lk+2][lr] = wv4.z; sWV[lk+3][lr] = wv4.w;
        __syncthreads();
        #pragma unroll
        for (int kk = 0; kk < 16; ++kk) {
            float ax[4], av[4], bm[4], bv[4], bw2[4];
            *(float4*)ax = *(const float4*)&sX [kk][tm << 2];
            *(float4*)av = *(const float4*)&sVX[kk][tm << 2];
            *(float4*)bm = *(const float4*)&sWM[kk][tn << 2];
            *(float4*)bv = *(const float4*)&sWV[kk][tn << 2];
            #pragma unroll
            for (int j = 0; j < 4; ++j) bw2[j] = fmaf(bm[j], bm[j], bv[j]);
            #pragma unroll
            for (int i = 0; i < 4; ++i) {
                const float xx = ax[i] * ax[i];
                #pragma unroll
                for (int j = 0; j < 4; ++j) {
                    accq[i][j] = fmaf(ax[i], bm[j], accq[i][j]);
                    accv[i][j] = fmaf(av[i], bw2[j], fmaf(xx, bv[j], accv[i][j]));
                }
            }
        }
    }

    const int h = blockIdx.x;
    #pragma unroll
    for (int i = 0; i < 4; ++i) {
        const int m = m0 + (tm << 2) + i;
        const int b = m >> 10;
        const int srow = m & 1023;
        const size_t o = (((size_t)b * NH + h) * NS + srow) * NDH + (tn << 2);
        *(float4*)(q_ws  + o) = make_float4(accq[i][0], accq[i][1], accq[i][2], accq[i][3]);
        *(float4*)(vq_ws + o) = make_float4(accv[i][0], accv[i][1], accv[i][2], accv[i][3]);
    }
}

// ---------------------------------------------------------------------------
// Kernel 2: fused causal attention with VDP variance propagation.
// LDS = 80 KiB exactly -> 2 blocks/CU (was 128 KiB -> 1 block/CU).
// K/V tiles staged as bf16 derived planes; per-row coefficients broadcast
// from registers via readlane (no sC buffer, no mid-loop barrier).
// ---------------------------------------------------------------------------
__global__ __launch_bounds__(512, 4)
void attn_vdp_kernel(const float* __restrict__ q_ws, const float* __restrict__ vq_ws,
                     const float* __restrict__ K,  const float* __restrict__ VK,
                     const float* __restrict__ Vv, const float* __restrict__ VV,
                     const float* __restrict__ x,
                     float* __restrict__ out0, float* __restrict__ out1)
{
    __shared__ float sQ[64][128];                 // 32 KiB: (q, var_q) fp32 pairs
    __shared__ unsigned short sKm [64][64];       // 8 KiB [dh][j^dh]  k mean
    __shared__ unsigned short sKk2[64][64];       // 8 KiB             k^2 + var_k
    __shared__ unsigned short sKv [64][64];       // 8 KiB             var_k
    __shared__ unsigned short sVm [64][64];       // 8 KiB [j][dh]     v mean
    __shared__ unsigned short sVw [64][64];       // 8 KiB             v^2 + var_v
    __shared__ unsigned short sVv [64][64];       // 8 KiB             var_v

    const int tid  = threadIdx.x;
    const int wv   = tid >> 6;
    const int lane = tid & 63;

    const int blk = blockIdx.x;
    const int qb  = 15 - (blk & 15);              // heavy blocks first
    const int bh  = blk >> 4;
    const int b   = bh >> 4;
    const int h   = bh & 15;
    const size_t kvbase = (size_t)bh * NS * NDH;
    const int row0 = qb * 64;

    // stage Q block (q, var_q interleaved fp32)
    #pragma unroll
    for (int it = 0; it < 8; ++it) {
        const int pos = tid + it * 512;
        const int r = pos >> 6, d = pos & 63;
        const size_t g = kvbase + (size_t)(row0 + r) * NDH + d;
        *(float2*)&sQ[r][d << 1] = make_float2(q_ws[g], vq_ws[g]);
    }

    float m_[8], Z_[8], S2_[8], N1[8], N2w[8], N2uw[8], N3uw[8], N2vv[8];
    #pragma unroll
    for (int r = 0; r < 8; ++r) {
        m_[r] = -INFINITY; Z_[r] = 0.f; S2_[r] = 0.f;
        N1[r] = 0.f; N2w[r] = 0.f; N2uw[r] = 0.f; N3uw[r] = 0.f; N2vv[r] = 0.f;
    }

    const int r0 = wv << 3;
    const int nt = qb + 1;
    for (int t = 0; t < nt; ++t) {
        const int j0 = t << 6;
        __syncthreads();   // previous tile fully consumed (also covers Q staging)
        #pragma unroll
        for (int it = 0; it < 8; ++it) {
            const int pos = tid + it * 512;
            const int jr = pos >> 6, d = pos & 63;
            const size_t g = kvbase + (size_t)(j0 + jr) * NDH + d;
            const float km = K[g],  kv = VK[g];
            const float vm = Vv[g], vv = VV[g];
            sKm [d][jr ^ d] = f2b(km);
            sKk2[d][jr ^ d] = f2b(fmaf(km, km, kv));
            sKv [d][jr ^ d] = f2b(kv);
            sVm[jr][d] = f2b(vm);
            sVw[jr][d] = f2b(fmaf(vm, vm, vv));
            sVv[jr][d] = f2b(vv);
        }
        __syncthreads();

        // ---- phase 1: lane = j, score mean/variance dots over dh ----
        float a_[8] = {}, u_[8] = {};
        #pragma unroll 8
        for (int dh = 0; dh < 64; ++dh) {
            const int c = lane ^ dh;
            const float km  = b2f(sKm [dh][c]);
            const float kk2 = b2f(sKk2[dh][c]);
            const float kv  = b2f(sKv [dh][c]);
            #pragma unroll
            for (int r = 0; r < 8; ++r) {
                const float2 qp = *(const float2*)&sQ[r0 + r][dh << 1];
                a_[r] = fmaf(qp.x, km, a_[r]);
                u_[r] = fmaf(qp.y, kk2, fmaf(qp.x * qp.x, kv, u_[r]));
            }
        }

        // ---- online softmax update per row (in-wave only) ----
        #pragma unroll
        for (int r = 0; r < 8; ++r) {
            const int irow = row0 + r0 + r;
            float a = a_[r] * 0.03125f;              // / sqrt(D)
            const float u = u_[r] * 0.0009765625f;   // / D
            if (j0 + lane > irow) a = -INFINITY;     // causal mask (mean path)
            float tmax = a;
            #pragma unroll
            for (int s_ = 32; s_; s_ >>= 1) tmax = fmaxf(tmax, __shfl_xor(tmax, s_));
            const float mnew = fmaxf(m_[r], tmax);
            const float e  = __expf(a - mnew);       // 0 for masked lanes
            const float s1 = __expf(m_[r] - mnew);
            m_[r] = mnew;
            float Zt = e, S2t = e * e * u;
            #pragma unroll
            for (int s_ = 32; s_; s_ >>= 1) { Zt += __shfl_xor(Zt, s_); S2t += __shfl_xor(S2t, s_); }
            const float s2 = s1 * s1, s3 = s2 * s1;
            Z_[r]  = fmaf(Z_[r],  s1, Zt);
            S2_[r] = fmaf(S2_[r], s2, S2t);
            N1[r] *= s1; N2w[r] *= s2; N2uw[r] *= s2; N3uw[r] *= s3; N2vv[r] *= s2;
            a_[r] = e;      // keep e in register (lane = j)
            u_[r] = u;      // keep u in register (lane = j)
        }

        // ---- phase 2: lane = dh; e,u broadcast from registers via readlane ----
        #pragma unroll 4
        for (int j = 0; j < 64; ++j) {
            const float vm = b2f(sVm[j][lane]);
            const float w  = b2f(sVw[j][lane]);
            const float vv = b2f(sVv[j][lane]);
            #pragma unroll
            for (int r = 0; r < 8; ++r) {
                const float ee = __uint_as_float(__builtin_amdgcn_readlane(__float_as_uint(a_[r]), j));
                const float uu = __uint_as_float(__builtin_amdgcn_readlane(__float_as_uint(u_[r]), j));
                const float c2  = ee * ee;
                const float c2u = c2 * uu;
                const float c3u = c2u * ee;
                N1[r]   = fmaf(ee,  vm, N1[r]);
                N2w[r]  = fmaf(c2,  w,  N2w[r]);
                N2uw[r] = fmaf(c2u, w,  N2uw[r]);
                N3uw[r] = fmaf(c3u, w,  N3uw[r]);
                N2vv[r] = fmaf(c2,  vv, N2vv[r]);
            }
        }
    }

    // epilogue
    #pragma unroll
    for (int r = 0; r < 8; ++r) {
        const int irow = row0 + r0 + r;
        const float rZ  = 1.0f / Z_[r];
        const float rZ2 = rZ * rZ;
        const float s   = S2_[r] * rZ2;
        const float Om  = N1[r] * rZ;
        const float Vo  = rZ2 * (fmaf(s, N2w[r], N2uw[r] + N2vv[r])) - 2.0f * rZ2 * rZ * N3uw[r];
        const size_t o = ((size_t)b * NS + irow) * ND + (h << 6) + lane;
        out0[o] = x[o] + Om;
        out1[o] = Vo;
    }
}

extern "C" void kernel_launch(void* const* d_in, const int* in_sizes, int n_in,
                              void* d_out, int out_size, void* d_ws, size_t ws_size,
                              hipStream_t stream)
{
    (void)in_sizes; (void)n_in; (void)out_size; (void)ws_size;
    const float* x  = (const float*)d_in[0];
    const float* vx = (const float*)d_in[1];
    const float* K  = (const float*)d_in[2];
    const float* VK = (const float*)d_in[3];
    const float* Vv = (const float*)d_in[4];
    const float* VV = (const float*)d_in[5];
    const float* Wm = (const float*)d_in[6];
    const float* Wv = (const float*)d_in[7];

    float* out0 = (float*)d_out;
    float* out1 = out0 + (size_t)NB * NS * ND;
    float* q_ws  = (float*)d_ws;
    float* vq_ws = q_ws + (size_t)NB * NH * NS * NDH;

    dim3 g1(ND / 64, (NB * NS) / 64);
    qproj_kernel<<<g1, 256, 0, stream>>>(x, vx, Wm, Wv, q_ws, vq_ws);
    attn_vdp_kernel<<<NB * NH * (NS / 64), 512, 0, stream>>>(q_ws, vq_ws, K, VK, Vv, VV, x, out0, out1);
}